// Round 9
// baseline (1298.977 us; speedup 1.0000x reference)
//
#include <hip/hip_runtime.h>
#include <cstdint>
#include <cstddef>

// Problem constants (Swin window attention)
#define B_WIN   2048
#define N_TOK   64
#define C_DIM   512
#define H_HEADS 16
#define D_HEAD  32
#define K_DIM   512
#define M_ROWS  (B_WIN * 64)   // 131072

// Tiled operand layout for pre-split bf16 operands (B weights, av):
//   T[mb][kt][s][r][e]  mb=row>>7, kt=k>>5, s=(k>>3)&3, r=row&127, e=k&7
//   flat elem = mb*65536 + kt*4096 + s*1024 + r*8 + e
// Chunk c (16B) within a 128x32 tile: s = c>>7, r = c&127.

typedef __bf16 bf16x8 __attribute__((ext_vector_type(8)));
typedef float  f32x4  __attribute__((ext_vector_type(4)));
typedef unsigned short u16x8 __attribute__((ext_vector_type(8)));

__device__ __forceinline__ unsigned short f2bf_rn(float f) {
    unsigned u = __float_as_uint(f);
    u += 0x7fffu + ((u >> 16) & 1u);
    return (unsigned short)(u >> 16);
}
__device__ __forceinline__ float bf2f(unsigned short h) {
    return __uint_as_float(((unsigned)h) << 16);
}
__device__ __forceinline__ void gload16(const void* g, void* l) {
    __builtin_amdgcn_global_load_lds(
        (const __attribute__((address_space(1))) void*)g,
        (__attribute__((address_space(3))) void*)l,
        16, 0, 0);
}

// ---------------------------------------------------------------------------
// bias_expand: bias_hn[h][i][j] = table[rel[i][j]][h]   (65536 floats)
// ---------------------------------------------------------------------------
__global__ void bias_expand_kernel(const float* __restrict__ bias_table,
                                   const int* __restrict__ rel_index,
                                   float* __restrict__ bias_hn) {
    int tid = blockIdx.x * 256 + threadIdx.x;
    int h  = tid >> 12;
    int ij = tid & 4095;
    bias_hn[tid] = bias_table[rel_index[ij] * H_HEADS + h];
}

// ---------------------------------------------------------------------------
// wsplit: w[512 k][Ncols n] -> wTh/wTl (rows=n, 512 k) in TILED layout
// ---------------------------------------------------------------------------
__global__ __launch_bounds__(256) void wsplit_kernel(
    const float* __restrict__ w,
    unsigned short* __restrict__ wTh,
    unsigned short* __restrict__ wTl,
    int Ncols)
{
    size_t e8 = ((size_t)blockIdx.x * 256 + threadIdx.x) * 8;
    const int mb = (int)(e8 >> 16);
    const int ww = (int)(e8 & 65535);
    const int kt = ww >> 12;
    const int s  = (ww >> 10) & 3;
    const int r  = (ww >> 3) & 127;
    const int n  = mb * 128 + r;
    const int k  = kt * 32 + s * 8;
    u16x8 hi, lo;
#pragma unroll
    for (int j = 0; j < 8; ++j) {
        float v = w[(size_t)(k + j) * Ncols + n];
        unsigned short h = f2bf_rn(v);
        hi[j] = h;
        lo[j] = f2bf_rn(v - bf2f(h));
    }
    *reinterpret_cast<u16x8*>(&wTh[e8]) = hi;
    *reinterpret_cast<u16x8*>(&wTl[e8]) = lo;
}

// ---------------------------------------------------------------------------
// bf16x3-split MFMA GEMM, 128x128 tile, BK=32, 16 steps, 8 waves.
// A reg-staged with 2-STEP lead:
//   FUSED:    A = x fp32 row-major; split to hi/lo in-kernel (xsplit fused)
//             chunk t -> row m0+(t&127), k-octet t>>7   [R8 BUGFIX]
//   !FUSED:   A = pre-split tiled bf16 (av from attention), identity chunks
// B staged via global_load_lds, 1-step lead. Issue order pinned with
// sched_barrier(0) so the counted vmcnt(2) provably leaves only the A(ks+2)
// reg-loads in flight (in-order vmcnt retire).
// ---------------------------------------------------------------------------
template<bool FUSED>
__global__ __launch_bounds__(512, 4) void gemm_mfma_kernel(
    const float* __restrict__ Afp,           // FUSED: x [M][512] fp32
    const unsigned short* __restrict__ ATh,  // !FUSED: tiled bf16 hi
    const unsigned short* __restrict__ ATl,  // !FUSED: tiled bf16 lo
    const unsigned short* __restrict__ BTh,  // tiled bf16 hi
    const unsigned short* __restrict__ BTl,  // tiled bf16 lo
    int mode,
    float* __restrict__ qkv_out,
    const float* __restrict__ bias,
    float* __restrict__ out,
    int Ncols_out,
    int nb_grid)
{
    __shared__ __align__(16) unsigned short L[2][4][4096];  // op: Ah Al Bh Bl

    const int t    = threadIdx.x;
    const int lane = t & 63;
    const int wave = t >> 6;             // 0..7
    const int lg   = lane >> 4;          // k-octet 0..3
    const int lr   = lane & 15;          // row within fragment
    const int wrow = (wave >> 1) * 32;   // 0,32,64,96
    const int wcol = (wave & 1) * 64;    // 0,64

    const int lin = blockIdx.x + gridDim.x * blockIdx.y;
    const int nwg = gridDim.x * gridDim.y;
    const int cpx = nwg >> 3;
    const int swz = (lin & 7) * cpx + (lin >> 3);
    const int m0  = (swz / nb_grid) * 128;
    const int n0  = (swz % nb_grid) * 128;
    const size_t tbA = (size_t)(m0 >> 7) * 16 * 4096;
    const size_t tbB = (size_t)(n0 >> 7) * 16 * 4096;

    f32x4 acc[2][4];
#pragma unroll
    for (int i = 0; i < 2; ++i)
#pragma unroll
        for (int j = 0; j < 4; ++j) acc[i][j] = (f32x4){0.f, 0.f, 0.f, 0.f};

    // pending A register sets (2-deep)
    float4 a0[2], a1[2];     // FUSED
    u16x8  nh[2], nl[2];     // !FUSED

    auto issueA = [&](int kt, int s) {
        if constexpr (FUSED) {
            // chunk t -> tiled (r = t&127, oct = t>>7)  [R8 bug was (t>>2, t&3)]
            const float* p = &Afp[(size_t)(m0 + (t & 127)) * 512 + kt * 32 + (t >> 7) * 8];
            a0[s] = *reinterpret_cast<const float4*>(p);
            a1[s] = *reinterpret_cast<const float4*>(p + 4);
        } else {
            const size_t bA = tbA + (size_t)kt * 4096 + (size_t)t * 8;
            nh[s] = *reinterpret_cast<const u16x8*>(&ATh[bA]);
            nl[s] = *reinterpret_cast<const u16x8*>(&ATl[bA]);
        }
    };
    auto writeA = [&](int s, int bi) {
        u16x8 hi, lo;
        if constexpr (FUSED) {
            float f[8] = {a0[s].x, a0[s].y, a0[s].z, a0[s].w,
                          a1[s].x, a1[s].y, a1[s].z, a1[s].w};
#pragma unroll
            for (int j = 0; j < 8; ++j) {
                unsigned short hh = f2bf_rn(f[j]);
                hi[j] = hh;
                lo[j] = f2bf_rn(f[j] - bf2f(hh));
            }
        } else {
            hi = nh[s];
            lo = nl[s];
        }
        *reinterpret_cast<u16x8*>(&L[bi][0][t * 8]) = hi;
        *reinterpret_cast<u16x8*>(&L[bi][1][t * 8]) = lo;
    };
    auto stageB = [&](int kt, int bi) {
        const size_t bB = tbB + (size_t)kt * 4096 + (size_t)t * 8;
        gload16(&BTh[bB], &L[bi][2][t * 8]);
        gload16(&BTl[bB], &L[bi][3][t * 8]);
    };

    // prologue: B(0) -> LDS; A(0),A(1) -> regs; A(0) -> LDS
    stageB(0, 0);
    __builtin_amdgcn_sched_barrier(0);   // pin: B DMA issued before A loads
    issueA(0, 0);
    issueA(1, 1);
    __builtin_amdgcn_sched_barrier(0);
    writeA(0, 0);   // convert waits A(0) (vmcnt<=2) => B(0) landed too (older)
    asm volatile("s_waitcnt lgkmcnt(0)" ::: "memory");
    __builtin_amdgcn_sched_barrier(0);
    __builtin_amdgcn_s_barrier();
    __builtin_amdgcn_sched_barrier(0);

#pragma unroll 2
    for (int ks = 0; ks < 16; ++ks) {
        const int cur = ks & 1;
        if (ks + 1 < 16) stageB(ks + 1, cur ^ 1);
        __builtin_amdgcn_sched_barrier(0);   // pin: B before A in vmem queue
        if (ks + 2 < 16) issueA(ks + 2, cur);   // set `cur` freed last iter
        __builtin_amdgcn_sched_barrier(0);   // pin: both issued before compute

        bf16x8 ah[2], al[2];
#pragma unroll
        for (int mi = 0; mi < 2; ++mi) {
            const int off = lg * 1024 + (wrow + mi * 16 + lr) * 8;
            ah[mi] = *reinterpret_cast<const bf16x8*>(&L[cur][0][off]);
            al[mi] = *reinterpret_cast<const bf16x8*>(&L[cur][1][off]);
        }
        __builtin_amdgcn_s_setprio(1);
#pragma unroll
        for (int ni = 0; ni < 4; ++ni) {
            const int off = lg * 1024 + (wcol + ni * 16 + lr) * 8;
            bf16x8 bh = *reinterpret_cast<const bf16x8*>(&L[cur][2][off]);
            bf16x8 bl = *reinterpret_cast<const bf16x8*>(&L[cur][3][off]);
#pragma unroll
            for (int mi = 0; mi < 2; ++mi) {
                acc[mi][ni] = __builtin_amdgcn_mfma_f32_16x16x32_bf16(ah[mi], bh, acc[mi][ni], 0, 0, 0);
                acc[mi][ni] = __builtin_amdgcn_mfma_f32_16x16x32_bf16(ah[mi], bl, acc[mi][ni], 0, 0, 0);
                acc[mi][ni] = __builtin_amdgcn_mfma_f32_16x16x32_bf16(al[mi], bh, acc[mi][ni], 0, 0, 0);
            }
        }
        __builtin_amdgcn_s_setprio(0);

        // convert+write A(ks+1) into next buffer (compiler inserts the
        // vmcnt wait for A(ks+1)'s reg-loads; A(ks+2)+B(ks+1) stay in flight)
        if (ks + 1 < 16) writeA(cur ^ 1, cur ^ 1);

        // counted drain: leaves only A(ks+2) reg-loads (the 2 newest) in
        // flight; B(ks+1) DMA (older) has retired (in-order vmcnt).
        if (ks < 14) {
            asm volatile("s_waitcnt vmcnt(2)" ::: "memory");
        } else {
            asm volatile("s_waitcnt vmcnt(0)" ::: "memory");
        }
        __builtin_amdgcn_sched_barrier(0);
        asm volatile("s_waitcnt lgkmcnt(0)" ::: "memory");
        __builtin_amdgcn_sched_barrier(0);
        __builtin_amdgcn_s_barrier();
        __builtin_amdgcn_sched_barrier(0);
    }

    // C/D layout: col = lane&15, row = (lane>>4)*4 + reg   [m89-verified]
    if (mode == 0) {
#pragma unroll
        for (int mi = 0; mi < 2; ++mi)
#pragma unroll
            for (int ni = 0; ni < 4; ++ni) {
                const int col  = n0 + wcol + ni * 16 + lr;
                const int tsel = col >> 9;
                const int h    = (col >> 5) & 15;
                const int dd   = col & 31;
#pragma unroll
                for (int reg = 0; reg < 4; ++reg) {
                    const int row = m0 + wrow + mi * 16 + lg * 4 + reg;
                    const int b = row >> 6, n = row & 63;
                    qkv_out[((((size_t)tsel * B_WIN + b) * H_HEADS + h) * N_TOK + n) * D_HEAD + dd]
                        = acc[mi][ni][reg];
                }
            }
    } else {
#pragma unroll
        for (int mi = 0; mi < 2; ++mi)
#pragma unroll
            for (int ni = 0; ni < 4; ++ni) {
                const int col = n0 + wcol + ni * 16 + lr;
                const float pb = bias[col];
#pragma unroll
                for (int reg = 0; reg < 4; ++reg) {
                    const int row = m0 + wrow + mi * 16 + lg * 4 + reg;
                    out[(size_t)row * Ncols_out + col] = acc[mi][ni][reg] + pb;
                }
            }
    }
}

// ---------------------------------------------------------------------------
// MFMA window attention (unchanged from R6/R7 — proven)
// ---------------------------------------------------------------------------
__global__ __launch_bounds__(256, 4) void attn_kernel(
    const float* __restrict__ qkv,        // [3][B][H][N][D]
    const float* __restrict__ bias_hn,    // [H][64][64]
    float* __restrict__ attn_map,         // [B][H][64][64]
    unsigned short* __restrict__ avh,     // tiled bf16 hi
    unsigned short* __restrict__ avl)     // tiled bf16 lo
{
    __shared__ __align__(16) unsigned short SM[14848];
    constexpr int QH = 0, QL = 2560, KH = 5120, KL = 7680;   // [64][40]
    constexpr int PH = 0, PL = 4608;                         // [64][72]
    constexpr int VTH = 10240, VTL = 12544;                  // [32][72]

    const int bh   = blockIdx.x;
    const int b    = bh >> 4;
    const int h    = bh & 15;
    const int t    = threadIdx.x;
    const int lane = t & 63;
    const int wv   = t >> 6;
    const int lg   = lane >> 4;
    const int lr   = lane & 15;

    const size_t plane = (size_t)B_WIN * H_HEADS * N_TOK * D_HEAD;
    const size_t base  = (size_t)bh * (N_TOK * D_HEAD);
    const float* qg = qkv + base;
    const float* kg = qkv + plane + base;
    const float* vg = qkv + 2 * plane + base;

    {
        const int r  = t >> 2;
        const int c0 = (t & 3) * 8;
        float4 a0 = *reinterpret_cast<const float4*>(&qg[r * 32 + c0]);
        float4 a1 = *reinterpret_cast<const float4*>(&qg[r * 32 + c0 + 4]);
        float qv[8] = {a0.x, a0.y, a0.z, a0.w, a1.x, a1.y, a1.z, a1.w};
        u16x8 hi, lo;
#pragma unroll
        for (int j = 0; j < 8; ++j) {
            unsigned short hh = f2bf_rn(qv[j]);
            hi[j] = hh; lo[j] = f2bf_rn(qv[j] - bf2f(hh));
        }
        *reinterpret_cast<u16x8*>(&SM[QH + r * 40 + c0]) = hi;
        *reinterpret_cast<u16x8*>(&SM[QL + r * 40 + c0]) = lo;

        float4 k0 = *reinterpret_cast<const float4*>(&kg[r * 32 + c0]);
        float4 k1 = *reinterpret_cast<const float4*>(&kg[r * 32 + c0 + 4]);
        float kv[8] = {k0.x, k0.y, k0.z, k0.w, k1.x, k1.y, k1.z, k1.w};
#pragma unroll
        for (int j = 0; j < 8; ++j) {
            unsigned short hh = f2bf_rn(kv[j]);
            hi[j] = hh; lo[j] = f2bf_rn(kv[j] - bf2f(hh));
        }
        *reinterpret_cast<u16x8*>(&SM[KH + r * 40 + c0]) = hi;
        *reinterpret_cast<u16x8*>(&SM[KL + r * 40 + c0]) = lo;

        float4 v0 = *reinterpret_cast<const float4*>(&vg[r * 32 + c0]);
        float4 v1 = *reinterpret_cast<const float4*>(&vg[r * 32 + c0 + 4]);
        float vv[8] = {v0.x, v0.y, v0.z, v0.w, v1.x, v1.y, v1.z, v1.w};
#pragma unroll
        for (int u = 0; u < 8; ++u) {
            const int d = c0 + u;
            unsigned short hh = f2bf_rn(vv[u]);
            SM[VTH + d * 72 + r] = hh;
            SM[VTL + d * 72 + r] = f2bf_rn(vv[u] - bf2f(hh));
        }
    }
    __syncthreads();

    float bias[4][4];
#pragma unroll
    for (int reg = 0; reg < 4; ++reg)
#pragma unroll
        for (int c = 0; c < 4; ++c)
            bias[reg][c] = bias_hn[(h << 12) + ((wv * 16 + lg * 4 + reg) << 6) + c * 16 + lr];

    const int ar = wv * 16 + lr;
    bf16x8 qa_h = *reinterpret_cast<const bf16x8*>(&SM[QH + ar * 40 + lg * 8]);
    bf16x8 qa_l = *reinterpret_cast<const bf16x8*>(&SM[QL + ar * 40 + lg * 8]);
    f32x4 S[4];
#pragma unroll
    for (int c = 0; c < 4; ++c) {
        const int br = c * 16 + lr;
        bf16x8 kb_h = *reinterpret_cast<const bf16x8*>(&SM[KH + br * 40 + lg * 8]);
        bf16x8 kb_l = *reinterpret_cast<const bf16x8*>(&SM[KL + br * 40 + lg * 8]);
        f32x4 s = (f32x4){0.f, 0.f, 0.f, 0.f};
        s = __builtin_amdgcn_mfma_f32_16x16x32_bf16(qa_h, kb_h, s, 0, 0, 0);
        s = __builtin_amdgcn_mfma_f32_16x16x32_bf16(qa_h, kb_l, s, 0, 0, 0);
        s = __builtin_amdgcn_mfma_f32_16x16x32_bf16(qa_l, kb_h, s, 0, 0, 0);
        S[c] = s;
    }
    __syncthreads();   // Q/K region dead -> reusable for P

    const float scale = 0.1767766952966369f;  // 32^-0.5
    float p[4][4], mx[4], sm[4];
#pragma unroll
    for (int reg = 0; reg < 4; ++reg) mx[reg] = -1e30f;
#pragma unroll
    for (int reg = 0; reg < 4; ++reg)
#pragma unroll
        for (int c = 0; c < 4; ++c) {
            float s = fmaf(S[c][reg], scale, bias[reg][c]);
            p[reg][c] = s;
            mx[reg] = fmaxf(mx[reg], s);
        }
#pragma unroll
    for (int reg = 0; reg < 4; ++reg) {
        mx[reg] = fmaxf(mx[reg], __shfl_xor(mx[reg], 1));
        mx[reg] = fmaxf(mx[reg], __shfl_xor(mx[reg], 2));
        mx[reg] = fmaxf(mx[reg], __shfl_xor(mx[reg], 4));
        mx[reg] = fmaxf(mx[reg], __shfl_xor(mx[reg], 8));
        sm[reg] = 0.f;
    }
#pragma unroll
    for (int reg = 0; reg < 4; ++reg)
#pragma unroll
        for (int c = 0; c < 4; ++c) {
            float e = __expf(p[reg][c] - mx[reg]);
            p[reg][c] = e;
            sm[reg] += e;
        }
#pragma unroll
    for (int reg = 0; reg < 4; ++reg) {
        sm[reg] += __shfl_xor(sm[reg], 1);
        sm[reg] += __shfl_xor(sm[reg], 2);
        sm[reg] += __shfl_xor(sm[reg], 4);
        sm[reg] += __shfl_xor(sm[reg], 8);
        const float inv = 1.0f / sm[reg];
#pragma unroll
        for (int c = 0; c < 4; ++c) p[reg][c] *= inv;
    }

    const size_t amb = (size_t)bh * 4096;
#pragma unroll
    for (int reg = 0; reg < 4; ++reg) {
        const int R = wv * 16 + lg * 4 + reg;
#pragma unroll
        for (int c = 0; c < 4; ++c) {
            const int C = c * 16 + lr;
            const float own = p[reg][c];
            attn_map[amb + R * 64 + C] = own;
            const float mate = __shfl_xor(own, 1);
            if (!(lr & 1)) {
                unsigned short h0 = f2bf_rn(own);
                unsigned short l0 = f2bf_rn(own - bf2f(h0));
                unsigned short h1 = f2bf_rn(mate);
                unsigned short l1 = f2bf_rn(mate - bf2f(h1));
                *reinterpret_cast<unsigned*>(&SM[PH + R * 72 + C]) =
                    (unsigned)h0 | ((unsigned)h1 << 16);
                *reinterpret_cast<unsigned*>(&SM[PL + R * 72 + C]) =
                    (unsigned)l0 | ((unsigned)l1 << 16);
            }
        }
    }
    // no barrier: wave w's PV a-frags read rows 16wv..16wv+15 = its own writes

    f32x4 O[2];
    O[0] = (f32x4){0.f, 0.f, 0.f, 0.f};
    O[1] = (f32x4){0.f, 0.f, 0.f, 0.f};
#pragma unroll
    for (int kk = 0; kk < 2; ++kk) {
        const int pr = wv * 16 + lr;
        bf16x8 pa_h = *reinterpret_cast<const bf16x8*>(&SM[PH + pr * 72 + kk * 32 + lg * 8]);
        bf16x8 pa_l = *reinterpret_cast<const bf16x8*>(&SM[PL + pr * 72 + kk * 32 + lg * 8]);
#pragma unroll
        for (int n = 0; n < 2; ++n) {
            const int vr = n * 16 + lr;
            bf16x8 vb_h = *reinterpret_cast<const bf16x8*>(&SM[VTH + vr * 72 + kk * 32 + lg * 8]);
            bf16x8 vb_l = *reinterpret_cast<const bf16x8*>(&SM[VTL + vr * 72 + kk * 32 + lg * 8]);
            O[n] = __builtin_amdgcn_mfma_f32_16x16x32_bf16(pa_h, vb_h, O[n], 0, 0, 0);
            O[n] = __builtin_amdgcn_mfma_f32_16x16x32_bf16(pa_h, vb_l, O[n], 0, 0, 0);
            O[n] = __builtin_amdgcn_mfma_f32_16x16x32_bf16(pa_l, vb_h, O[n], 0, 0, 0);
        }
    }

    const int mb = b >> 1;
#pragma unroll
    for (int n = 0; n < 2; ++n)
#pragma unroll
        for (int reg = 0; reg < 4; ++reg) {
            const int R  = wv * 16 + lg * 4 + reg;
            const int d  = n * 16 + lr;
            const int rl = (b & 1) * 64 + R;
            const float o = O[n][reg];
            unsigned short oh = f2bf_rn(o);
            unsigned short ol = f2bf_rn(o - bf2f(oh));
            size_t off = (size_t)mb * 65536 + (size_t)h * 4096
                       + (size_t)(d >> 3) * 1024 + (size_t)rl * 8 + (d & 7);
            avh[off] = oh;
            avl[off] = ol;
        }
}

// ---------------------------------------------------------------------------
extern "C" void kernel_launch(void* const* d_in, const int* in_sizes, int n_in,
                              void* d_out, int out_size, void* d_ws, size_t ws_size,
                              hipStream_t stream) {
    const float* x          = (const float*)d_in[0];
    const float* qkv_w      = (const float*)d_in[1];
    const float* proj_w     = (const float*)d_in[2];
    const float* proj_b     = (const float*)d_in[3];
    const float* bias_table = (const float*)d_in[4];
    const int*   rel_index  = (const int*)d_in[5];

    float* out      = (float*)d_out;                           // [131072][512]
    float* attn_map = (float*)d_out + (size_t)M_ROWS * C_DIM;  // [B][H][64][64]

    // d_ws: avh | avl (tiled bf16, written by attn) | qkv fp32
    unsigned short* avh = (unsigned short*)d_ws;
    unsigned short* avl = avh + (size_t)M_ROWS * 512;
    float*          qkv = (float*)(avl + (size_t)M_ROWS * 512);

    // parking: qkv_w split -> attn_map region of d_out (dead until attn
    // overwrites it); proj_w split -> qkv head (dead after attn reads qkv);
    // bias_hn -> out head (out written only by the final proj GEMM).
    unsigned short* qwTh = (unsigned short*)attn_map;
    unsigned short* qwTl = qwTh + (size_t)1536 * 512;
    unsigned short* pwTh = (unsigned short*)qkv;
    unsigned short* pwTl = pwTh + (size_t)512 * 512;
    float* bias_hn = out;   // 65536 floats at head of out region

    bias_expand_kernel<<<256, 256, 0, stream>>>(bias_table, rel_index, bias_hn);
    wsplit_kernel<<<384, 256, 0, stream>>>(qkv_w, qwTh, qwTl, 1536);
    gemm_mfma_kernel<true><<<dim3(12, 1024), 512, 0, stream>>>(
        x, nullptr, nullptr, qwTh, qwTl, 0, qkv, nullptr, nullptr, 1536, 12);
    attn_kernel<<<B_WIN * H_HEADS, 256, 0, stream>>>(
        qkv, bias_hn, attn_map, avh, avl);
    wsplit_kernel<<<128, 256, 0, stream>>>(proj_w, pwTh, pwTl, 512);
    gemm_mfma_kernel<false><<<dim3(4, 1024), 512, 0, stream>>>(
        nullptr, avh, avl, pwTh, pwTl, 1, nullptr, proj_b, out, 512, 4);
}